// Round 12
// baseline (187.585 us; speedup 1.0000x reference)
//
#include <hip/hip_runtime.h>
#include <hip/hip_bf16.h>

// Problem constants
#define BSZ 4
#define SEQ 2048
#define NH  16
#define DH  64
#define TOK (BSZ*SEQ)          // 8192 tokens
#define PROJC (NH*DH)          // 1024

typedef __bf16 bf16x8 __attribute__((ext_vector_type(8)));
typedef float  f32x4  __attribute__((ext_vector_type(4)));
typedef float  f32x16 __attribute__((ext_vector_type(16)));
typedef unsigned int uint4v __attribute__((ext_vector_type(4)));
typedef unsigned int uint2v __attribute__((ext_vector_type(2)));

__device__ inline unsigned short f2bf(float f) {
    __bf16 h = (__bf16)f;
    return __builtin_bit_cast(unsigned short, h);
}

__device__ inline bf16x8 ld8(const unsigned short* p) {
    return __builtin_bit_cast(bf16x8, *reinterpret_cast<const uint4v*>(p));
}

// raw v_exp_f32 (2^x): 1 instruction, no OCML range/denorm guards.
__device__ inline float fexp2(float x) {
    float r;
    asm("v_exp_f32 %0, %1" : "=v"(r) : "v"(x));
    return r;
}

// async global -> LDS, 16B per lane; LDS dest = wave-uniform base + lane*16
__device__ inline void gload16(const unsigned short* g, unsigned short* l) {
    __builtin_amdgcn_global_load_lds(
        (__attribute__((address_space(1))) void*)g,
        (__attribute__((address_space(3))) void*)l, 16, 0, 0);
}

// ---------------- fused prep: conv (f32->bf16) + 4x weight transpose -------
__global__ __launch_bounds__(256) void prep_kernel(const float* __restrict__ q,
                                                   const float* __restrict__ k,
                                                   const float* __restrict__ Wq,
                                                   const float* __restrict__ Wk,
                                                   const float* __restrict__ Wv,
                                                   const float* __restrict__ Wfc,
                                                   unsigned short* __restrict__ qbf,
                                                   unsigned short* __restrict__ kbf,
                                                   unsigned short* __restrict__ WqT,
                                                   unsigned short* __restrict__ WkT,
                                                   unsigned short* __restrict__ WvT,
                                                   unsigned short* __restrict__ WfcT) {
    int bx = blockIdx.x;
    if (bx < 4096) {
        int idx = (bx & 2047) * 256 + threadIdx.x;
        if (bx < 2048) qbf[idx] = f2bf(q[idx]);
        else           kbf[idx] = f2bf(k[idx]);
        return;
    }
    bx -= 4096;
    const float* W; unsigned short* WT; int cols; int base;
    if      (bx < 256) { W = Wq;  WT = WqT;  cols = PROJC; base = bx; }
    else if (bx < 512) { W = Wk;  WT = WkT;  cols = PROJC; base = bx - 256; }
    else if (bx < 768) { W = Wv;  WT = WvT;  cols = PROJC; base = bx - 512; }
    else               { W = Wfc; WT = WfcT; cols = 64;    base = bx - 768; }
    int idx = base * 256 + threadIdx.x;
    int c = idx % cols, kk = idx / cols;
    WT[c * 64 + kk] = f2bf(W[kk * cols + c]);
}

// ---------------- mask bit-pack: int32 [b][q][k] -> uint64 bitrows ---------
__global__ __launch_bounds__(256) void maskpack_kernel(const int* __restrict__ mask,
                                                       unsigned long long* __restrict__ mbits) {
    size_t gid = (size_t)blockIdx.x * 256 + threadIdx.x;
    int lane = threadIdx.x & 63;
    unsigned long long bal = __ballot(mask[gid] != 0);
    if (lane == 0) mbits[gid >> 6] = bal;
}

// ---------------- projections: tokens x 64 @ 64 x 1024 ---------------------
__global__ __launch_bounds__(256) void proj_kernel(const unsigned short* __restrict__ qbf,
                                                   const unsigned short* __restrict__ kbf,
                                                   const unsigned short* __restrict__ WqT,
                                                   const unsigned short* __restrict__ WkT,
                                                   const unsigned short* __restrict__ WvT,
                                                   unsigned short* __restrict__ Qo,
                                                   unsigned short* __restrict__ Ko,
                                                   unsigned short* __restrict__ Vto) {
    int z = blockIdx.z;
    const unsigned short* A  = (z == 0) ? qbf : kbf;
    const unsigned short* WT = (z == 0) ? WqT : (z == 1) ? WkT : WvT;
    int tid = threadIdx.x, w = tid >> 6, lane = tid & 63;
    int l15 = lane & 15, l4 = lane >> 4;
    int r0 = blockIdx.x * 64 + w * 16;
    int c0 = blockIdx.y * 64;
    int h = blockIdx.y;
    int b = r0 >> 11;
    size_t bh = (size_t)(b * NH + h);

    const unsigned short* ap = A + (r0 + l15) * 64 + l4 * 8;
    bf16x8 a0 = ld8(ap), a1 = ld8(ap + 32);

    for (int ct = 0; ct < 4; ++ct) {
        const unsigned short* wp = WT + (c0 + ct * 16 + l15) * 64 + l4 * 8;
        bf16x8 b0 = ld8(wp), b1 = ld8(wp + 32);
        f32x4 acc = {0.f, 0.f, 0.f, 0.f};
        if (z == 2) {
            acc = __builtin_amdgcn_mfma_f32_16x16x32_bf16(a0, b0, acc, 0, 0, 0);
            acc = __builtin_amdgcn_mfma_f32_16x16x32_bf16(a1, b1, acc, 0, 0, 0);
        } else {
            acc = __builtin_amdgcn_mfma_f32_16x16x32_bf16(b0, a0, acc, 0, 0, 0);
            acc = __builtin_amdgcn_mfma_f32_16x16x32_bf16(b1, a1, acc, 0, 0, 0);
        }
        uint2v pk;
        pk.x = (unsigned)f2bf(acc[0]) | ((unsigned)f2bf(acc[1]) << 16);
        pk.y = (unsigned)f2bf(acc[2]) | ((unsigned)f2bf(acc[3]) << 16);
        if (z == 2) {
            int dd = ct * 16 + l15;
            int q0 = (r0 + l4 * 4) & 2047;
            *reinterpret_cast<uint2v*>(Vto + (bh * 64 + dd) * SEQ + q0) = pk;
        } else {
            int qq = (r0 + l15) & 2047;
            unsigned short* dst = (z == 0) ? Qo : Ko;
            *reinterpret_cast<uint2v*>(dst + (bh * SEQ + qq) * 64 + ct * 16 + l4 * 4) = pk;
        }
    }
}

// ---------------- flash attention: 32x32 MFMA, P fully in-register ---------
// Grid 1024 (XCD-swizzled), 256 threads = 4 waves, 32 q rows per wave.
// K/V tiles [64][64] double-buffered in LDS via global_load_lds (linear dest,
// XOR-16B-swizzled source; reads apply the same XOR). Swapped QK^T: lane
// (q=lane&31, hi) holds S[q][k=(reg&3)+8*(reg>>2)+4*hi]. PV k-slices chosen
// as the union of the two half-wave k-sets, so the PV A-frag is the lane's
// own 4 packed words (no cross-lane, no P LDS). ell via ones-MFMA in O's
// D-layout. Static max m=0; fully-masked rows -> ell==0 -> 0 (nan_to_num).
// R9-proven softmax path: mask folded as 0/-inf bias in fma before v_exp_f32.
// (R10/R11 bias-in-MFMA-C experiment failed twice unexplained -- reverted.)
__global__ __launch_bounds__(256, 4) void attn_kernel(const unsigned short* __restrict__ Q,
                                                      const unsigned short* __restrict__ K,
                                                      const unsigned short* __restrict__ Vt,
                                                      const unsigned long long* __restrict__ mbits,
                                                      unsigned short* __restrict__ O) {
    __shared__ __align__(16) unsigned short Ks[2][64 * 64];   // 16 KB
    __shared__ __align__(16) unsigned short Vs[2][64 * 64];   // 16 KB
    int tid = threadIdx.x, w = tid >> 6, lane = tid & 63;
    int l31 = lane & 31, hi = lane >> 5;
    int hi4 = hi * 4;

    // XCD-aware swizzle: 1024 % 8 == 0, bijective
    int bid = blockIdx.x;
    int swz = (bid & 7) * 128 + (bid >> 3);
    int bh = swz >> 4;              // 0..63
    int qt = swz & 15;              // 0..15
    int b = bh >> 4;
    int qbase = qt * 128 + w * 32;

    const unsigned short* Qh = Q  + (size_t)bh * SEQ * 64;
    const unsigned short* Kh = K  + (size_t)bh * SEQ * 64;
    const unsigned short* Vh = Vt + (size_t)bh * 64 * SEQ;
    const unsigned long long* mrow =
        mbits + ((size_t)b * SEQ + qbase + l31) * (SEQ / 64);

    // staging geometry: chunk idx = w*64 + lane (+256), row = idx>>3, col16 = idx&7
    int row1 = (w << 3) + (lane >> 3);          // 0..31
    int row2 = row1 + 32;
    int sc1 = (lane & 7) ^ (row1 & 7);          // source chunk (XOR involution)
    unsigned short* Kd0 = &Ks[0][0] + w * 512;
    unsigned short* Vd0 = &Vs[0][0] + w * 512;
    unsigned short* Kd1 = &Ks[1][0] + w * 512;
    unsigned short* Vd1 = &Vs[1][0] + w * 512;

    // Q B-frags: lane holds Q[qbase+l31][s*16 + hi*8 + j]
    bf16x8 qf[4];
    #pragma unroll
    for (int s = 0; s < 4; ++s)
        qf[s] = ld8(Qh + (size_t)(qbase + l31) * 64 + s * 16 + hi * 8);

    bf16x8 ones;
    #pragma unroll
    for (int i = 0; i < 8; ++i) ones[i] = (__bf16)1.0f;

    f32x16 o0 = {0.f,0.f,0.f,0.f,0.f,0.f,0.f,0.f,0.f,0.f,0.f,0.f,0.f,0.f,0.f,0.f};
    f32x16 o1 = o0;
    f32x16 ellD = o0;
    const float C = 0.125f * 1.44269504088896f;   // scale * log2(e)

    // prologue: stage kb=0 into buffer 0
    gload16(Kh + (size_t)row1 * 64 + sc1 * 8, Kd0);
    gload16(Kh + (size_t)row2 * 64 + sc1 * 8, Kd0 + 2048);
    gload16(Vh + (size_t)row1 * SEQ + sc1 * 8, Vd0);
    gload16(Vh + (size_t)row2 * SEQ + sc1 * 8, Vd0 + 2048);
    __syncthreads();

    int cur = 0;
    for (int kb = 0; kb < SEQ; kb += 64) {
        // ---- stage next tile (async DMA, in flight across compute)
        if (kb + 64 < SEQ) {
            int nkb = kb + 64;
            unsigned short* Kd = cur ? Kd0 : Kd1;
            unsigned short* Vd = cur ? Vd0 : Vd1;
            gload16(Kh + (size_t)(nkb + row1) * 64 + sc1 * 8, Kd);
            gload16(Kh + (size_t)(nkb + row2) * 64 + sc1 * 8, Kd + 2048);
            gload16(Vh + (size_t)row1 * SEQ + nkb + sc1 * 8, Vd);
            gload16(Vh + (size_t)row2 * SEQ + nkb + sc1 * 8, Vd + 2048);
        }
        unsigned long long wb = mrow[kb >> 6];
        const unsigned short* Kc = &Ks[cur][0];
        const unsigned short* Vc = &Vs[cur][0];

        #pragma unroll
        for (int kt = 0; kt < 2; ++kt) {
            // ---- QK^T (swapped): z[reg] = S[q=l31][k=kt*32+(reg&3)+8*(reg>>2)+4hi]
            f32x16 z = {0.f,0.f,0.f,0.f,0.f,0.f,0.f,0.f,0.f,0.f,0.f,0.f,0.f,0.f,0.f,0.f};
            int krow = kt * 32 + l31;
            #pragma unroll
            for (int s = 0; s < 4; ++s) {
                const unsigned short* kp =
                    Kc + krow * 64 + ((((s << 1) + hi) ^ (krow & 7)) << 3);
                z = __builtin_amdgcn_mfma_f32_32x32x16_bf16(ld8(kp), qf[s], z, 0, 0, 0);
            }
            // ---- mask (0/-inf bias via bfe) + v_exp_f32 + pack to bf16 pairs
            unsigned wsh = (unsigned)(wb >> (kt * 32)) >> hi4;  // lane's bits at 0..27
            unsigned wpk[8];
            #pragma unroll
            for (int rq = 0; rq < 4; ++rq) {
                #pragma unroll
                for (int rr = 0; rr < 2; ++rr) {
                    float e[2];
                    #pragma unroll
                    for (int j = 0; j < 2; ++j) {
                        int pos = rq * 8 + 2 * rr + j;          // compile-time
                        int sx = (int)(wsh << (31 - pos)) >> 31; // v_bfe_i32
                        float bias = __builtin_bit_cast(float, (unsigned)sx & 0xFF800000u);
                        e[j] = fexp2(__builtin_fmaf(z[rq * 4 + 2 * rr + j], C, bias));
                    }
                    wpk[rq * 2 + rr] = (unsigned)f2bf(e[0]) | ((unsigned)f2bf(e[1]) << 16);
                }
            }
            // ---- ell + PV: A-frag = own words (k-subset trick), V matches
            __builtin_amdgcn_s_setprio(1);
            #pragma unroll
            for (int sl = 0; sl < 2; ++sl) {
                uint4v aw = {wpk[sl * 4 + 0], wpk[sl * 4 + 1],
                             wpk[sl * 4 + 2], wpk[sl * 4 + 3]};
                bf16x8 af = __builtin_bit_cast(bf16x8, aw);
                ellD = __builtin_amdgcn_mfma_f32_32x32x16_bf16(af, ones, ellD, 0, 0, 0);
                int n = kt * 2 + sl;            // k-subtile of 16 within kb
                {   // dtile 0
                    int vrow = l31;
                    int c0i = ((2 * n) ^ (vrow & 7)) << 3;
                    int c1i = ((2 * n + 1) ^ (vrow & 7)) << 3;
                    uint2v lo = *reinterpret_cast<const uint2v*>(Vc + vrow * 64 + c0i + hi4);
                    uint2v hh = *reinterpret_cast<const uint2v*>(Vc + vrow * 64 + c1i + hi4);
                    uint4v vw = {lo.x, lo.y, hh.x, hh.y};
                    o0 = __builtin_amdgcn_mfma_f32_32x32x16_bf16(
                        af, __builtin_bit_cast(bf16x8, vw), o0, 0, 0, 0);
                }
                {   // dtile 1
                    int vrow = 32 + l31;
                    int c0i = ((2 * n) ^ (vrow & 7)) << 3;
                    int c1i = ((2 * n + 1) ^ (vrow & 7)) << 3;
                    uint2v lo = *reinterpret_cast<const uint2v*>(Vc + vrow * 64 + c0i + hi4);
                    uint2v hh = *reinterpret_cast<const uint2v*>(Vc + vrow * 64 + c1i + hi4);
                    uint4v vw = {lo.x, lo.y, hh.x, hh.y};
                    o1 = __builtin_amdgcn_mfma_f32_32x32x16_bf16(
                        af, __builtin_bit_cast(bf16x8, vw), o1, 0, 0, 0);
                }
            }
            __builtin_amdgcn_s_setprio(0);
        }
        __syncthreads();
        cur ^= 1;
    }
    // ---- normalize + store; lane holds O[q=(reg&3)+8*(reg>>2)+4hi][d=dt*32+l31]
    #pragma unroll
    for (int reg = 0; reg < 16; ++reg) {
        float l = ellD[reg];
        float rcp = (l == 0.f) ? 0.f : __builtin_amdgcn_rcpf(l);
        int ql = (reg & 3) + 8 * (reg >> 2) + hi4;
        size_t base = ((size_t)bh * SEQ + qbase + ql) * 64 + l31;
        O[base]      = f2bf(o0[reg] * rcp);
        O[base + 32] = f2bf(o1[reg] * rcp);
    }
}

// ---------------- FC + tanh: rows ordered (b, q, h), packed f32x4 stores ---
// Swapped MFMA (proj-pattern): lane's 4 D-values = 4 consecutive output cols
// for its own row -> one 16B store per ct. tanh via (t-1)/(t+1), t=exp2(..),
// x clamped to +-9 (err ~1e-7).
__global__ __launch_bounds__(256) void fc_kernel(const unsigned short* __restrict__ O,
                                                 const unsigned short* __restrict__ WfcT,
                                                 const float* __restrict__ bfc,
                                                 float* __restrict__ out) {
    int tid = threadIdx.x, w = tid >> 6, lane = tid & 63;
    int l15 = lane & 15, l4 = lane >> 4;
    int r0 = blockIdx.x * 64 + w * 16;

    int row = r0 + l15;
    int h = row & 15, t_ = row >> 4;
    int q = t_ & 2047, b = t_ >> 11;
    const unsigned short* op = O + (((size_t)(b * NH + h)) * SEQ + q) * 64 + l4 * 8;
    bf16x8 a0 = ld8(op), a1 = ld8(op + 32);

    for (int ct = 0; ct < 4; ++ct) {
        const unsigned short* wp = WfcT + (ct * 16 + l15) * 64 + l4 * 8;
        bf16x8 b0 = ld8(wp), b1 = ld8(wp + 32);
        f32x4 acc = {0.f, 0.f, 0.f, 0.f};
        acc = __builtin_amdgcn_mfma_f32_16x16x32_bf16(b0, a0, acc, 0, 0, 0);
        acc = __builtin_amdgcn_mfma_f32_16x16x32_bf16(b1, a1, acc, 0, 0, 0);
        // lane: row = r0 + l15, cols dd = ct*16 + l4*4 + 0..3
        f32x4 bv = *reinterpret_cast<const f32x4*>(bfc + ct * 16 + l4 * 4);
        f32x4 st;
        #pragma unroll
        for (int r = 0; r < 4; ++r) {
            float x = acc[r] + bv[r];
            x = fminf(fmaxf(x, -9.f), 9.f);
            float t = fexp2(x * 2.88539008177793f);     // 2*log2(e)
            st[r] = (t - 1.f) * __builtin_amdgcn_rcpf(t + 1.f);
        }
        *reinterpret_cast<f32x4*>(out + (size_t)row * 64 + ct * 16 + l4 * 4) = st;
    }
}

extern "C" void kernel_launch(void* const* d_in, const int* in_sizes, int n_in,
                              void* d_out, int out_size, void* d_ws, size_t ws_size,
                              hipStream_t stream) {
    const float* q_origin = (const float*)d_in[0];
    const float* k_origin = (const float*)d_in[1];
    const int*   mask     = (const int*)d_in[2];
    const float* Wq       = (const float*)d_in[3];
    const float* Wk       = (const float*)d_in[4];
    const float* Wv       = (const float*)d_in[5];
    const float* Wfc      = (const float*)d_in[6];
    const float* bfc      = (const float*)d_in[7];
    float* out = (float*)d_out;

    unsigned short* ws = (unsigned short*)d_ws;
    unsigned short* qbf  = ws;                 // dead after proj
    unsigned short* kbf  = qbf  + TOK * DH;    // dead after proj
    unsigned short* WqT  = kbf  + TOK * DH;
    unsigned short* WkT  = WqT  + 64 * PROJC;
    unsigned short* WvT  = WkT  + 64 * PROJC;
    unsigned short* WfcT = WvT  + 64 * PROJC;
    unsigned short* Qb   = WfcT + 64 * 64;
    unsigned short* Kb   = Qb   + (size_t)BSZ * NH * SEQ * DH;
    unsigned short* Vtb  = Kb   + (size_t)BSZ * NH * SEQ * DH;
    unsigned short* Ob   = Vtb  + (size_t)BSZ * NH * SEQ * DH;
    unsigned long long* mbits = (unsigned long long*)d_ws;  // aliases qbf/kbf

    prep_kernel<<<4880, 256, 0, stream>>>(q_origin, k_origin, Wq, Wk, Wv, Wfc,
                                          qbf, kbf, WqT, WkT, WvT, WfcT);
    proj_kernel<<<dim3(TOK / 64, PROJC / 64, 3), 256, 0, stream>>>(
        qbf, kbf, WqT, WkT, WvT, Qb, Kb, Vtb);
    maskpack_kernel<<<(size_t)BSZ * SEQ * SEQ / 256, 256, 0, stream>>>(mask, mbits);
    attn_kernel<<<1024, 256, 0, stream>>>(Qb, Kb, Vtb, mbits, Ob);
    fc_kernel<<<(size_t)BSZ * SEQ * NH / 64, 256, 0, stream>>>(Ob, WfcT, bfc, out);
}

// Round 13
// 183.169 us; speedup vs baseline: 1.0241x; 1.0241x over previous
//
#include <hip/hip_runtime.h>
#include <hip/hip_bf16.h>

// Problem constants
#define BSZ 4
#define SEQ 2048
#define NH  16
#define DH  64
#define TOK (BSZ*SEQ)          // 8192 tokens
#define PROJC (NH*DH)          // 1024

typedef __bf16 bf16x8 __attribute__((ext_vector_type(8)));
typedef float  f32x4  __attribute__((ext_vector_type(4)));
typedef float  f32x16 __attribute__((ext_vector_type(16)));
typedef unsigned int uint4v __attribute__((ext_vector_type(4)));
typedef unsigned int uint2v __attribute__((ext_vector_type(2)));

__device__ inline unsigned short f2bf(float f) {
    __bf16 h = (__bf16)f;
    return __builtin_bit_cast(unsigned short, h);
}

__device__ inline bf16x8 ld8(const unsigned short* p) {
    return __builtin_bit_cast(bf16x8, *reinterpret_cast<const uint4v*>(p));
}

// raw v_exp_f32 (2^x): 1 instruction, no OCML range/denorm guards.
__device__ inline float fexp2(float x) {
    float r;
    asm("v_exp_f32 %0, %1" : "=v"(r) : "v"(x));
    return r;
}

// async global -> LDS, 16B per lane; LDS dest = wave-uniform base + lane*16
__device__ inline void gload16(const unsigned short* g, unsigned short* l) {
    __builtin_amdgcn_global_load_lds(
        (__attribute__((address_space(1))) void*)g,
        (__attribute__((address_space(3))) void*)l, 16, 0, 0);
}

// ---------------- fused prep: conv (f32->bf16) + 4x weight transpose -------
__global__ __launch_bounds__(256) void prep_kernel(const float* __restrict__ q,
                                                   const float* __restrict__ k,
                                                   const float* __restrict__ Wq,
                                                   const float* __restrict__ Wk,
                                                   const float* __restrict__ Wv,
                                                   const float* __restrict__ Wfc,
                                                   unsigned short* __restrict__ qbf,
                                                   unsigned short* __restrict__ kbf,
                                                   unsigned short* __restrict__ WqT,
                                                   unsigned short* __restrict__ WkT,
                                                   unsigned short* __restrict__ WvT,
                                                   unsigned short* __restrict__ WfcT) {
    int bx = blockIdx.x;
    if (bx < 4096) {
        int idx = (bx & 2047) * 256 + threadIdx.x;
        if (bx < 2048) qbf[idx] = f2bf(q[idx]);
        else           kbf[idx] = f2bf(k[idx]);
        return;
    }
    bx -= 4096;
    const float* W; unsigned short* WT; int cols; int base;
    if      (bx < 256) { W = Wq;  WT = WqT;  cols = PROJC; base = bx; }
    else if (bx < 512) { W = Wk;  WT = WkT;  cols = PROJC; base = bx - 256; }
    else if (bx < 768) { W = Wv;  WT = WvT;  cols = PROJC; base = bx - 512; }
    else               { W = Wfc; WT = WfcT; cols = 64;    base = bx - 768; }
    int idx = base * 256 + threadIdx.x;
    int c = idx % cols, kk = idx / cols;
    WT[c * 64 + kk] = f2bf(W[kk * cols + c]);
}

// ---------------- mask bit-pack: int32 [b][q][k] -> uint64 bitrows ---------
__global__ __launch_bounds__(256) void maskpack_kernel(const int* __restrict__ mask,
                                                       unsigned long long* __restrict__ mbits) {
    size_t gid = (size_t)blockIdx.x * 256 + threadIdx.x;
    int lane = threadIdx.x & 63;
    unsigned long long bal = __ballot(mask[gid] != 0);
    if (lane == 0) mbits[gid >> 6] = bal;
}

// ---------------- projections: tokens x 64 @ 64 x 1024 ---------------------
// Compute as before (MFMA, packed 8B fragments), but route the 64x64 output
// tile through LDS so global stores are fully coalesced b128:
//   z!=2 (Q,K): T[row][col], write out rows of Q/K (1 KB contiguous per wave)
//   z==2 (V):   T[dd][q],   write out rows of Vt (128B segments per row)
__global__ __launch_bounds__(256) void proj_kernel(const unsigned short* __restrict__ qbf,
                                                   const unsigned short* __restrict__ kbf,
                                                   const unsigned short* __restrict__ WqT,
                                                   const unsigned short* __restrict__ WkT,
                                                   const unsigned short* __restrict__ WvT,
                                                   unsigned short* __restrict__ Qo,
                                                   unsigned short* __restrict__ Ko,
                                                   unsigned short* __restrict__ Vto) {
    __shared__ __align__(16) unsigned short T[64][72];
    int z = blockIdx.z;
    const unsigned short* A  = (z == 0) ? qbf : kbf;
    const unsigned short* WT = (z == 0) ? WqT : (z == 1) ? WkT : WvT;
    int tid = threadIdx.x, w = tid >> 6, lane = tid & 63;
    int l15 = lane & 15, l4 = lane >> 4;
    int r0 = blockIdx.x * 64 + w * 16;
    int c0 = blockIdx.y * 64;
    int b = blockIdx.x >> 5;                 // token block 64 -> batch
    size_t bh = (size_t)(b * NH + blockIdx.y);

    const unsigned short* ap = A + (r0 + l15) * 64 + l4 * 8;
    bf16x8 a0 = ld8(ap), a1 = ld8(ap + 32);

    #pragma unroll
    for (int ct = 0; ct < 4; ++ct) {
        const unsigned short* wp = WT + (c0 + ct * 16 + l15) * 64 + l4 * 8;
        bf16x8 b0 = ld8(wp), b1 = ld8(wp + 32);
        f32x4 acc = {0.f, 0.f, 0.f, 0.f};
        if (z == 2) {
            acc = __builtin_amdgcn_mfma_f32_16x16x32_bf16(a0, b0, acc, 0, 0, 0);
            acc = __builtin_amdgcn_mfma_f32_16x16x32_bf16(a1, b1, acc, 0, 0, 0);
        } else {
            acc = __builtin_amdgcn_mfma_f32_16x16x32_bf16(b0, a0, acc, 0, 0, 0);
            acc = __builtin_amdgcn_mfma_f32_16x16x32_bf16(b1, a1, acc, 0, 0, 0);
        }
        uint2v pk;
        pk.x = (unsigned)f2bf(acc[0]) | ((unsigned)f2bf(acc[1]) << 16);
        pk.y = (unsigned)f2bf(acc[2]) | ((unsigned)f2bf(acc[3]) << 16);
        if (z == 2) {
            // acc[r] = Vt[dd = ct*16+l15][q_local = w*16 + l4*4 + r]
            *reinterpret_cast<uint2v*>(&T[ct * 16 + l15][w * 16 + l4 * 4]) = pk;
        } else {
            // acc[r] = out[row_local = w*16+l15][col = ct*16 + l4*4 + r]
            *reinterpret_cast<uint2v*>(&T[w * 16 + l15][ct * 16 + l4 * 4]) = pk;
        }
    }
    __syncthreads();

    // coalesced write-out: 2 passes x 16B per thread
    int rl8 = tid >> 3, chunk = tid & 7;
    int q0 = (blockIdx.x & 31) * 64;         // token offset within batch
    if (z == 2) {
        #pragma unroll
        for (int p = 0; p < 2; ++p) {
            int dd = p * 32 + rl8;
            uint4v v = *reinterpret_cast<const uint4v*>(&T[dd][chunk * 8]);
            *reinterpret_cast<uint4v*>(Vto + (bh * 64 + dd) * SEQ + q0 + chunk * 8) = v;
        }
    } else {
        unsigned short* dst = (z == 0) ? Qo : Ko;
        #pragma unroll
        for (int p = 0; p < 2; ++p) {
            int rl = p * 32 + rl8;
            uint4v v = *reinterpret_cast<const uint4v*>(&T[rl][chunk * 8]);
            *reinterpret_cast<uint4v*>(dst + (bh * SEQ + q0 + rl) * 64 + chunk * 8) = v;
        }
    }
}

// ---------------- flash attention: 32x32 MFMA, P fully in-register ---------
// Grid 1024 (XCD-swizzled), 256 threads = 4 waves, 32 q rows per wave.
// K/V tiles [64][64] double-buffered in LDS via global_load_lds (linear dest,
// XOR-16B-swizzled source; reads apply the same XOR). kb-loop UNROLLED x2 so
// the double-buffer selection is compile-time (no pointer cndmask, static
// addressing). Swapped QK^T: lane (q=lane&31, hi) holds
// S[q][k=(reg&3)+8*(reg>>2)+4*hi]. PV A-frag = lane's own packed words
// (k-subset trick, no cross-lane, no P LDS). ell via ones-MFMA in O's
// D-layout. Static max m=0; fully-masked rows -> ell==0 -> 0 (nan_to_num).
// R9-proven softmax: mask folded as 0/-inf bias in fma before v_exp_f32.
__global__ __launch_bounds__(256, 4) void attn_kernel(const unsigned short* __restrict__ Q,
                                                      const unsigned short* __restrict__ K,
                                                      const unsigned short* __restrict__ Vt,
                                                      const unsigned long long* __restrict__ mbits,
                                                      unsigned short* __restrict__ O) {
    __shared__ __align__(16) unsigned short Ks[2][64 * 64];   // 16 KB
    __shared__ __align__(16) unsigned short Vs[2][64 * 64];   // 16 KB
    int tid = threadIdx.x, w = tid >> 6, lane = tid & 63;
    int l31 = lane & 31, hi = lane >> 5;
    int hi4 = hi * 4;

    // XCD-aware swizzle: 1024 % 8 == 0, bijective
    int bid = blockIdx.x;
    int swz = (bid & 7) * 128 + (bid >> 3);
    int bh = swz >> 4;              // 0..63
    int qt = swz & 15;              // 0..15
    int b = bh >> 4;
    int qbase = qt * 128 + w * 32;

    const unsigned short* Qh = Q  + (size_t)bh * SEQ * 64;
    const unsigned short* Kh = K  + (size_t)bh * SEQ * 64;
    const unsigned short* Vh = Vt + (size_t)bh * 64 * SEQ;
    const unsigned long long* mrow =
        mbits + ((size_t)b * SEQ + qbase + l31) * (SEQ / 64);

    // staging geometry: chunk idx = w*64 + lane (+256), row = idx>>3, col16 = idx&7
    int row1 = (w << 3) + (lane >> 3);          // 0..31
    int row2 = row1 + 32;
    int sc1 = (lane & 7) ^ (row1 & 7);          // source chunk (XOR involution)
    unsigned short* Kd0 = &Ks[0][0] + w * 512;
    unsigned short* Vd0 = &Vs[0][0] + w * 512;
    unsigned short* Kd1 = &Ks[1][0] + w * 512;
    unsigned short* Vd1 = &Vs[1][0] + w * 512;

    // Q B-frags: lane holds Q[qbase+l31][s*16 + hi*8 + j]
    bf16x8 qf[4];
    #pragma unroll
    for (int s = 0; s < 4; ++s)
        qf[s] = ld8(Qh + (size_t)(qbase + l31) * 64 + s * 16 + hi * 8);

    bf16x8 ones;
    #pragma unroll
    for (int i = 0; i < 8; ++i) ones[i] = (__bf16)1.0f;

    f32x16 o0 = {0.f,0.f,0.f,0.f,0.f,0.f,0.f,0.f,0.f,0.f,0.f,0.f,0.f,0.f,0.f,0.f};
    f32x16 o1 = o0;
    f32x16 ellD = o0;
    const float C = 0.125f * 1.44269504088896f;   // scale * log2(e)

    auto stage_tile = [&](unsigned short* Kd, unsigned short* Vd, int nkb) {
        gload16(Kh + (size_t)(nkb + row1) * 64 + sc1 * 8, Kd);
        gload16(Kh + (size_t)(nkb + row2) * 64 + sc1 * 8, Kd + 2048);
        gload16(Vh + (size_t)row1 * SEQ + nkb + sc1 * 8, Vd);
        gload16(Vh + (size_t)row2 * SEQ + nkb + sc1 * 8, Vd + 2048);
    };

    auto compute_tile = [&](const unsigned short* Kc, const unsigned short* Vc, int kb) {
        unsigned long long wb = mrow[kb >> 6];
        #pragma unroll
        for (int kt = 0; kt < 2; ++kt) {
            f32x16 z = {0.f,0.f,0.f,0.f,0.f,0.f,0.f,0.f,0.f,0.f,0.f,0.f,0.f,0.f,0.f,0.f};
            int krow = kt * 32 + l31;
            #pragma unroll
            for (int s = 0; s < 4; ++s) {
                const unsigned short* kp =
                    Kc + krow * 64 + ((((s << 1) + hi) ^ (krow & 7)) << 3);
                z = __builtin_amdgcn_mfma_f32_32x32x16_bf16(ld8(kp), qf[s], z, 0, 0, 0);
            }
            unsigned wsh = (unsigned)(wb >> (kt * 32)) >> hi4;  // lane's bits 0..27
            unsigned wpk[8];
            #pragma unroll
            for (int rq = 0; rq < 4; ++rq) {
                #pragma unroll
                for (int rr = 0; rr < 2; ++rr) {
                    float e[2];
                    #pragma unroll
                    for (int j = 0; j < 2; ++j) {
                        int pos = rq * 8 + 2 * rr + j;           // compile-time
                        int sx = (int)(wsh << (31 - pos)) >> 31; // v_bfe_i32
                        float bias = __builtin_bit_cast(float, (unsigned)sx & 0xFF800000u);
                        e[j] = fexp2(__builtin_fmaf(z[rq * 4 + 2 * rr + j], C, bias));
                    }
                    wpk[rq * 2 + rr] = (unsigned)f2bf(e[0]) | ((unsigned)f2bf(e[1]) << 16);
                }
            }
            __builtin_amdgcn_s_setprio(1);
            #pragma unroll
            for (int sl = 0; sl < 2; ++sl) {
                uint4v aw = {wpk[sl * 4 + 0], wpk[sl * 4 + 1],
                             wpk[sl * 4 + 2], wpk[sl * 4 + 3]};
                bf16x8 af = __builtin_bit_cast(bf16x8, aw);
                ellD = __builtin_amdgcn_mfma_f32_32x32x16_bf16(af, ones, ellD, 0, 0, 0);
                int n = kt * 2 + sl;            // k-subtile of 16 within kb
                {   // dtile 0
                    int vrow = l31;
                    int c0i = ((2 * n) ^ (vrow & 7)) << 3;
                    int c1i = ((2 * n + 1) ^ (vrow & 7)) << 3;
                    uint2v lo = *reinterpret_cast<const uint2v*>(Vc + vrow * 64 + c0i + hi4);
                    uint2v hh = *reinterpret_cast<const uint2v*>(Vc + vrow * 64 + c1i + hi4);
                    uint4v vw = {lo.x, lo.y, hh.x, hh.y};
                    o0 = __builtin_amdgcn_mfma_f32_32x32x16_bf16(
                        af, __builtin_bit_cast(bf16x8, vw), o0, 0, 0, 0);
                }
                {   // dtile 1
                    int vrow = 32 + l31;
                    int c0i = ((2 * n) ^ (vrow & 7)) << 3;
                    int c1i = ((2 * n + 1) ^ (vrow & 7)) << 3;
                    uint2v lo = *reinterpret_cast<const uint2v*>(Vc + vrow * 64 + c0i + hi4);
                    uint2v hh = *reinterpret_cast<const uint2v*>(Vc + vrow * 64 + c1i + hi4);
                    uint4v vw = {lo.x, lo.y, hh.x, hh.y};
                    o1 = __builtin_amdgcn_mfma_f32_32x32x16_bf16(
                        af, __builtin_bit_cast(bf16x8, vw), o1, 0, 0, 0);
                }
            }
            __builtin_amdgcn_s_setprio(0);
        }
    };

    // prologue: stage kb=0 into buffer 0
    stage_tile(Kd0, Vd0, 0);
    __syncthreads();

    // unrolled x2: buffer roles are compile-time static
    for (int kb = 0; kb < SEQ; kb += 128) {
        // phase A: compute buf0 (tile kb), stage kb+64 -> buf1 (kb+64 <= 1984)
        stage_tile(Kd1, Vd1, kb + 64);
        compute_tile(&Ks[0][0], &Vs[0][0], kb);
        __syncthreads();
        // phase B: compute buf1 (tile kb+64), stage kb+128 -> buf0 (unless last)
        if (kb + 128 < SEQ) stage_tile(Kd0, Vd0, kb + 128);
        compute_tile(&Ks[1][0], &Vs[1][0], kb + 64);
        __syncthreads();
    }
    // ---- normalize + store; lane holds O[q=(reg&3)+8*(reg>>2)+4hi][d=dt*32+l31]
    #pragma unroll
    for (int reg = 0; reg < 16; ++reg) {
        float l = ellD[reg];
        float rcp = (l == 0.f) ? 0.f : __builtin_amdgcn_rcpf(l);
        int ql = (reg & 3) + 8 * (reg >> 2) + hi4;
        size_t base = ((size_t)bh * SEQ + qbase + ql) * 64 + l31;
        O[base]      = f2bf(o0[reg] * rcp);
        O[base + 32] = f2bf(o1[reg] * rcp);
    }
}

// ---------------- FC + tanh: rows ordered (b, q, h), packed f32x4 stores ---
__global__ __launch_bounds__(256) void fc_kernel(const unsigned short* __restrict__ O,
                                                 const unsigned short* __restrict__ WfcT,
                                                 const float* __restrict__ bfc,
                                                 float* __restrict__ out) {
    int tid = threadIdx.x, w = tid >> 6, lane = tid & 63;
    int l15 = lane & 15, l4 = lane >> 4;
    int r0 = blockIdx.x * 64 + w * 16;

    int row = r0 + l15;
    int h = row & 15, t_ = row >> 4;
    int q = t_ & 2047, b = t_ >> 11;
    const unsigned short* op = O + (((size_t)(b * NH + h)) * SEQ + q) * 64 + l4 * 8;
    bf16x8 a0 = ld8(op), a1 = ld8(op + 32);

    for (int ct = 0; ct < 4; ++ct) {
        const unsigned short* wp = WfcT + (ct * 16 + l15) * 64 + l4 * 8;
        bf16x8 b0 = ld8(wp), b1 = ld8(wp + 32);
        f32x4 acc = {0.f, 0.f, 0.f, 0.f};
        acc = __builtin_amdgcn_mfma_f32_16x16x32_bf16(b0, a0, acc, 0, 0, 0);
        acc = __builtin_amdgcn_mfma_f32_16x16x32_bf16(b1, a1, acc, 0, 0, 0);
        // lane: row = r0 + l15, cols dd = ct*16 + l4*4 + 0..3
        f32x4 bv = *reinterpret_cast<const f32x4*>(bfc + ct * 16 + l4 * 4);
        f32x4 st;
        #pragma unroll
        for (int r = 0; r < 4; ++r) {
            float x = acc[r] + bv[r];
            x = fminf(fmaxf(x, -9.f), 9.f);
            float t = fexp2(x * 2.88539008177793f);     // 2*log2(e)
            st[r] = (t - 1.f) * __builtin_amdgcn_rcpf(t + 1.f);
        }
        *reinterpret_cast<f32x4*>(out + (size_t)row * 64 + ct * 16 + l4 * 4) = st;
    }
}

extern "C" void kernel_launch(void* const* d_in, const int* in_sizes, int n_in,
                              void* d_out, int out_size, void* d_ws, size_t ws_size,
                              hipStream_t stream) {
    const float* q_origin = (const float*)d_in[0];
    const float* k_origin = (const float*)d_in[1];
    const int*   mask     = (const int*)d_in[2];
    const float* Wq       = (const float*)d_in[3];
    const float* Wk       = (const float*)d_in[4];
    const float* Wv       = (const float*)d_in[5];
    const float* Wfc      = (const float*)d_in[6];
    const float* bfc      = (const float*)d_in[7];
    float* out = (float*)d_out;

    unsigned short* ws = (unsigned short*)d_ws;
    unsigned short* qbf  = ws;                 // dead after proj
    unsigned short* kbf  = qbf  + TOK * DH;    // dead after proj
    unsigned short* WqT  = kbf  + TOK * DH;
    unsigned short* WkT  = WqT  + 64 * PROJC;
    unsigned short* WvT  = WkT  + 64 * PROJC;
    unsigned short* WfcT = WvT  + 64 * PROJC;
    unsigned short* Qb   = WfcT + 64 * 64;
    unsigned short* Kb   = Qb   + (size_t)BSZ * NH * SEQ * DH;
    unsigned short* Vtb  = Kb   + (size_t)BSZ * NH * SEQ * DH;
    unsigned short* Ob   = Vtb  + (size_t)BSZ * NH * SEQ * DH;
    unsigned long long* mbits = (unsigned long long*)d_ws;  // aliases qbf/kbf

    prep_kernel<<<4880, 256, 0, stream>>>(q_origin, k_origin, Wq, Wk, Wv, Wfc,
                                          qbf, kbf, WqT, WkT, WvT, WfcT);
    proj_kernel<<<dim3(TOK / 64, PROJC / 64, 3), 256, 0, stream>>>(
        qbf, kbf, WqT, WkT, WvT, Qb, Kb, Vtb);
    maskpack_kernel<<<(size_t)BSZ * SEQ * SEQ / 256, 256, 0, stream>>>(mask, mbits);
    attn_kernel<<<1024, 256, 0, stream>>>(Qb, Kb, Vtb, mbits, Ob);
    fc_kernel<<<(size_t)BSZ * SEQ * NH / 64, 256, 0, stream>>>(Ob, WfcT, bfc, out);
}

// Round 14
// 175.039 us; speedup vs baseline: 1.0717x; 1.0464x over previous
//
#include <hip/hip_runtime.h>
#include <hip/hip_bf16.h>

// Problem constants
#define BSZ 4
#define SEQ 2048
#define NH  16
#define DH  64
#define TOK (BSZ*SEQ)          // 8192 tokens
#define PROJC (NH*DH)          // 1024

typedef __bf16 bf16x8 __attribute__((ext_vector_type(8)));
typedef float  f32x4  __attribute__((ext_vector_type(4)));
typedef float  f32x16 __attribute__((ext_vector_type(16)));
typedef unsigned int uint4v __attribute__((ext_vector_type(4)));
typedef unsigned int uint2v __attribute__((ext_vector_type(2)));

__device__ inline unsigned short f2bf(float f) {
    __bf16 h = (__bf16)f;
    return __builtin_bit_cast(unsigned short, h);
}

__device__ inline bf16x8 ld8(const unsigned short* p) {
    return __builtin_bit_cast(bf16x8, *reinterpret_cast<const uint4v*>(p));
}

// raw v_exp_f32 (2^x): 1 instruction, no OCML range/denorm guards.
__device__ inline float fexp2(float x) {
    float r;
    asm("v_exp_f32 %0, %1" : "=v"(r) : "v"(x));
    return r;
}

// async global -> LDS, 16B per lane; LDS dest = wave-uniform base + lane*16
__device__ inline void gload16(const unsigned short* g, unsigned short* l) {
    __builtin_amdgcn_global_load_lds(
        (__attribute__((address_space(1))) void*)g,
        (__attribute__((address_space(3))) void*)l, 16, 0, 0);
}

// ---------------- fused prep: conv (f32->bf16) + 4x weight transpose -------
__global__ __launch_bounds__(256) void prep_kernel(const float* __restrict__ q,
                                                   const float* __restrict__ k,
                                                   const float* __restrict__ Wq,
                                                   const float* __restrict__ Wk,
                                                   const float* __restrict__ Wv,
                                                   const float* __restrict__ Wfc,
                                                   unsigned short* __restrict__ qbf,
                                                   unsigned short* __restrict__ kbf,
                                                   unsigned short* __restrict__ WqT,
                                                   unsigned short* __restrict__ WkT,
                                                   unsigned short* __restrict__ WvT,
                                                   unsigned short* __restrict__ WfcT) {
    int bx = blockIdx.x;
    if (bx < 4096) {
        int idx = (bx & 2047) * 256 + threadIdx.x;
        if (bx < 2048) qbf[idx] = f2bf(q[idx]);
        else           kbf[idx] = f2bf(k[idx]);
        return;
    }
    bx -= 4096;
    const float* W; unsigned short* WT; int cols; int base;
    if      (bx < 256) { W = Wq;  WT = WqT;  cols = PROJC; base = bx; }
    else if (bx < 512) { W = Wk;  WT = WkT;  cols = PROJC; base = bx - 256; }
    else if (bx < 768) { W = Wv;  WT = WvT;  cols = PROJC; base = bx - 512; }
    else               { W = Wfc; WT = WfcT; cols = 64;    base = bx - 768; }
    int idx = base * 256 + threadIdx.x;
    int c = idx % cols, kk = idx / cols;
    WT[c * 64 + kk] = f2bf(W[kk * cols + c]);
}

// ---------------- mask bit-pack: int32 [b][q][k] -> uint64 bitrows ---------
__global__ __launch_bounds__(256) void maskpack_kernel(const int* __restrict__ mask,
                                                       unsigned long long* __restrict__ mbits) {
    size_t gid = (size_t)blockIdx.x * 256 + threadIdx.x;
    int lane = threadIdx.x & 63;
    unsigned long long bal = __ballot(mask[gid] != 0);
    if (lane == 0) mbits[gid >> 6] = bal;
}

// ---------------- fused projections: Q, K, Vt in one pass ------------------
// Grid (128 token-tiles, 16 heads), 256 threads. A-fragments (qbf, kbf)
// loaded once; kbf shared between K and V. Outputs routed through three LDS
// tiles (one barrier), then written with coalesced b128 stores:
//   Q/K: T[row][col] -> contiguous rows;  Vt: T[dd][q] -> 128B row segments.
__global__ __launch_bounds__(256) void proj_kernel(const unsigned short* __restrict__ qbf,
                                                   const unsigned short* __restrict__ kbf,
                                                   const unsigned short* __restrict__ WqT,
                                                   const unsigned short* __restrict__ WkT,
                                                   const unsigned short* __restrict__ WvT,
                                                   unsigned short* __restrict__ Qo,
                                                   unsigned short* __restrict__ Ko,
                                                   unsigned short* __restrict__ Vto) {
    __shared__ __align__(16) unsigned short TQ[64][72];
    __shared__ __align__(16) unsigned short TK[64][72];
    __shared__ __align__(16) unsigned short TV[64][72];
    int tid = threadIdx.x, w = tid >> 6, lane = tid & 63;
    int l15 = lane & 15, l4 = lane >> 4;
    int r0 = blockIdx.x * 64 + w * 16;
    int h = blockIdx.y;
    int c0 = h * 64;
    int b = blockIdx.x >> 5;
    size_t bh = (size_t)(b * NH + h);

    const unsigned short* aq = qbf + (r0 + l15) * 64 + l4 * 8;
    bf16x8 a0q = ld8(aq), a1q = ld8(aq + 32);
    const unsigned short* ak = kbf + (r0 + l15) * 64 + l4 * 8;
    bf16x8 a0k = ld8(ak), a1k = ld8(ak + 32);

    #pragma unroll
    for (int ct = 0; ct < 4; ++ct) {
        int wrow = (c0 + ct * 16 + l15) * 64 + l4 * 8;
        bf16x8 q0 = ld8(WqT + wrow), q1 = ld8(WqT + wrow + 32);
        bf16x8 k0 = ld8(WkT + wrow), k1 = ld8(WkT + wrow + 32);
        bf16x8 v0 = ld8(WvT + wrow), v1 = ld8(WvT + wrow + 32);
        f32x4 accq = {0.f,0.f,0.f,0.f}, acck = accq, accv = accq;
        // Q, K: swapped (lane = one token row, 4 consecutive cols)
        accq = __builtin_amdgcn_mfma_f32_16x16x32_bf16(q0, a0q, accq, 0, 0, 0);
        accq = __builtin_amdgcn_mfma_f32_16x16x32_bf16(q1, a1q, accq, 0, 0, 0);
        acck = __builtin_amdgcn_mfma_f32_16x16x32_bf16(k0, a0k, acck, 0, 0, 0);
        acck = __builtin_amdgcn_mfma_f32_16x16x32_bf16(k1, a1k, acck, 0, 0, 0);
        // V: unswapped (lane = one dd col, 4 consecutive tokens)
        accv = __builtin_amdgcn_mfma_f32_16x16x32_bf16(a0k, v0, accv, 0, 0, 0);
        accv = __builtin_amdgcn_mfma_f32_16x16x32_bf16(a1k, v1, accv, 0, 0, 0);
        uint2v pq, pk, pv;
        pq.x = (unsigned)f2bf(accq[0]) | ((unsigned)f2bf(accq[1]) << 16);
        pq.y = (unsigned)f2bf(accq[2]) | ((unsigned)f2bf(accq[3]) << 16);
        pk.x = (unsigned)f2bf(acck[0]) | ((unsigned)f2bf(acck[1]) << 16);
        pk.y = (unsigned)f2bf(acck[2]) | ((unsigned)f2bf(acck[3]) << 16);
        pv.x = (unsigned)f2bf(accv[0]) | ((unsigned)f2bf(accv[1]) << 16);
        pv.y = (unsigned)f2bf(accv[2]) | ((unsigned)f2bf(accv[3]) << 16);
        *reinterpret_cast<uint2v*>(&TQ[w * 16 + l15][ct * 16 + l4 * 4]) = pq;
        *reinterpret_cast<uint2v*>(&TK[w * 16 + l15][ct * 16 + l4 * 4]) = pk;
        *reinterpret_cast<uint2v*>(&TV[ct * 16 + l15][w * 16 + l4 * 4]) = pv;
    }
    __syncthreads();

    int rl8 = tid >> 3, chunk = tid & 7;
    int q0 = (blockIdx.x & 31) * 64;
    #pragma unroll
    for (int p = 0; p < 2; ++p) {
        int rl = p * 32 + rl8;
        uint4v vq = *reinterpret_cast<const uint4v*>(&TQ[rl][chunk * 8]);
        uint4v vk = *reinterpret_cast<const uint4v*>(&TK[rl][chunk * 8]);
        uint4v vv = *reinterpret_cast<const uint4v*>(&TV[rl][chunk * 8]);
        *reinterpret_cast<uint4v*>(Qo  + (bh * SEQ + q0 + rl) * 64 + chunk * 8) = vq;
        *reinterpret_cast<uint4v*>(Ko  + (bh * SEQ + q0 + rl) * 64 + chunk * 8) = vk;
        *reinterpret_cast<uint4v*>(Vto + (bh * 64 + rl) * SEQ + q0 + chunk * 8) = vv;
    }
}

// ---------------- flash attention: 32x32 MFMA, P fully in-register ---------
// Grid 512 (XCD-swizzled), 512 threads = 8 waves, 32 q rows per wave; the 8
// waves of a block share ONE K/V staging (each bh tile staged 8x total, not
// 16x): per thread one gload16 for K + one for V per tile. K/V [64][64]
// double-buffered via global_load_lds (linear dest, XOR-16B-swizzled source;
// reads apply the same XOR); kb-loop unrolled x2 (compile-time buffers).
// Swapped QK^T; PV A-frag = lane's own packed words (k-subset trick); ell
// via ones-MFMA in O's D-layout. Static max m=0; fully-masked rows ->
// ell==0 -> 0 (nan_to_num). R9-proven softmax path.
__global__ __launch_bounds__(512, 4) void attn_kernel(const unsigned short* __restrict__ Q,
                                                      const unsigned short* __restrict__ K,
                                                      const unsigned short* __restrict__ Vt,
                                                      const unsigned long long* __restrict__ mbits,
                                                      unsigned short* __restrict__ O) {
    __shared__ __align__(16) unsigned short Ks[2][64 * 64];   // 16 KB
    __shared__ __align__(16) unsigned short Vs[2][64 * 64];   // 16 KB
    int tid = threadIdx.x, w = tid >> 6, lane = tid & 63;
    int l31 = lane & 31, hi = lane >> 5;
    int hi4 = hi * 4;

    // XCD-aware swizzle: 512 % 8 == 0, bijective
    int bid = blockIdx.x;
    int swz = (bid & 7) * 64 + (bid >> 3);
    int bh = swz >> 3;              // 0..63
    int qt = swz & 7;               // 0..7
    int b = bh >> 4;
    int qbase = qt * 256 + w * 32;

    const unsigned short* Qh = Q  + (size_t)bh * SEQ * 64;
    const unsigned short* Kh = K  + (size_t)bh * SEQ * 64;
    const unsigned short* Vh = Vt + (size_t)bh * 64 * SEQ;
    const unsigned long long* mrow =
        mbits + ((size_t)b * SEQ + qbase + l31) * (SEQ / 64);

    // staging: 512 threads x 16B = full 8KB tile in one pass
    int row1 = (w << 3) + (lane >> 3);          // 0..63 across 8 waves
    int sc1 = (lane & 7) ^ (row1 & 7);          // source chunk (XOR involution)
    unsigned short* Kd0 = &Ks[0][0] + w * 512;
    unsigned short* Vd0 = &Vs[0][0] + w * 512;
    unsigned short* Kd1 = &Ks[1][0] + w * 512;
    unsigned short* Vd1 = &Vs[1][0] + w * 512;

    // Q B-frags: lane holds Q[qbase+l31][s*16 + hi*8 + j]
    bf16x8 qf[4];
    #pragma unroll
    for (int s = 0; s < 4; ++s)
        qf[s] = ld8(Qh + (size_t)(qbase + l31) * 64 + s * 16 + hi * 8);

    bf16x8 ones;
    #pragma unroll
    for (int i = 0; i < 8; ++i) ones[i] = (__bf16)1.0f;

    f32x16 o0 = {0.f,0.f,0.f,0.f,0.f,0.f,0.f,0.f,0.f,0.f,0.f,0.f,0.f,0.f,0.f,0.f};
    f32x16 o1 = o0;
    f32x16 ellD = o0;
    const float C = 0.125f * 1.44269504088896f;   // scale * log2(e)

    auto stage_tile = [&](unsigned short* Kd, unsigned short* Vd, int nkb) {
        gload16(Kh + (size_t)(nkb + row1) * 64 + sc1 * 8, Kd);
        gload16(Vh + (size_t)row1 * SEQ + nkb + sc1 * 8, Vd);
    };

    auto compute_tile = [&](const unsigned short* Kc, const unsigned short* Vc, int kb) {
        unsigned long long wb = mrow[kb >> 6];
        #pragma unroll
        for (int kt = 0; kt < 2; ++kt) {
            f32x16 z = {0.f,0.f,0.f,0.f,0.f,0.f,0.f,0.f,0.f,0.f,0.f,0.f,0.f,0.f,0.f,0.f};
            int krow = kt * 32 + l31;
            #pragma unroll
            for (int s = 0; s < 4; ++s) {
                const unsigned short* kp =
                    Kc + krow * 64 + ((((s << 1) + hi) ^ (krow & 7)) << 3);
                z = __builtin_amdgcn_mfma_f32_32x32x16_bf16(ld8(kp), qf[s], z, 0, 0, 0);
            }
            unsigned wsh = (unsigned)(wb >> (kt * 32)) >> hi4;  // lane's bits 0..27
            unsigned wpk[8];
            #pragma unroll
            for (int rq = 0; rq < 4; ++rq) {
                #pragma unroll
                for (int rr = 0; rr < 2; ++rr) {
                    float e[2];
                    #pragma unroll
                    for (int j = 0; j < 2; ++j) {
                        int pos = rq * 8 + 2 * rr + j;           // compile-time
                        int sx = (int)(wsh << (31 - pos)) >> 31; // v_bfe_i32
                        float bias = __builtin_bit_cast(float, (unsigned)sx & 0xFF800000u);
                        e[j] = fexp2(__builtin_fmaf(z[rq * 4 + 2 * rr + j], C, bias));
                    }
                    wpk[rq * 2 + rr] = (unsigned)f2bf(e[0]) | ((unsigned)f2bf(e[1]) << 16);
                }
            }
            __builtin_amdgcn_s_setprio(1);
            #pragma unroll
            for (int sl = 0; sl < 2; ++sl) {
                uint4v aw = {wpk[sl * 4 + 0], wpk[sl * 4 + 1],
                             wpk[sl * 4 + 2], wpk[sl * 4 + 3]};
                bf16x8 af = __builtin_bit_cast(bf16x8, aw);
                ellD = __builtin_amdgcn_mfma_f32_32x32x16_bf16(af, ones, ellD, 0, 0, 0);
                int n = kt * 2 + sl;            // k-subtile of 16 within kb
                {   // dtile 0
                    int vrow = l31;
                    int c0i = ((2 * n) ^ (vrow & 7)) << 3;
                    int c1i = ((2 * n + 1) ^ (vrow & 7)) << 3;
                    uint2v lo = *reinterpret_cast<const uint2v*>(Vc + vrow * 64 + c0i + hi4);
                    uint2v hh = *reinterpret_cast<const uint2v*>(Vc + vrow * 64 + c1i + hi4);
                    uint4v vw = {lo.x, lo.y, hh.x, hh.y};
                    o0 = __builtin_amdgcn_mfma_f32_32x32x16_bf16(
                        af, __builtin_bit_cast(bf16x8, vw), o0, 0, 0, 0);
                }
                {   // dtile 1
                    int vrow = 32 + l31;
                    int c0i = ((2 * n) ^ (vrow & 7)) << 3;
                    int c1i = ((2 * n + 1) ^ (vrow & 7)) << 3;
                    uint2v lo = *reinterpret_cast<const uint2v*>(Vc + vrow * 64 + c0i + hi4);
                    uint2v hh = *reinterpret_cast<const uint2v*>(Vc + vrow * 64 + c1i + hi4);
                    uint4v vw = {lo.x, lo.y, hh.x, hh.y};
                    o1 = __builtin_amdgcn_mfma_f32_32x32x16_bf16(
                        af, __builtin_bit_cast(bf16x8, vw), o1, 0, 0, 0);
                }
            }
            __builtin_amdgcn_s_setprio(0);
        }
    };

    // prologue: stage kb=0 into buffer 0
    stage_tile(Kd0, Vd0, 0);
    __syncthreads();

    // unrolled x2: buffer roles are compile-time static
    for (int kb = 0; kb < SEQ; kb += 128) {
        stage_tile(Kd1, Vd1, kb + 64);
        compute_tile(&Ks[0][0], &Vs[0][0], kb);
        __syncthreads();
        if (kb + 128 < SEQ) stage_tile(Kd0, Vd0, kb + 128);
        compute_tile(&Ks[1][0], &Vs[1][0], kb + 64);
        __syncthreads();
    }
    // ---- normalize + store; lane holds O[q=(reg&3)+8*(reg>>2)+4hi][d=dt*32+l31]
    #pragma unroll
    for (int reg = 0; reg < 16; ++reg) {
        float l = ellD[reg];
        float rcp = (l == 0.f) ? 0.f : __builtin_amdgcn_rcpf(l);
        int ql = (reg & 3) + 8 * (reg >> 2) + hi4;
        size_t base = ((size_t)bh * SEQ + qbase + ql) * 64 + l31;
        O[base]      = f2bf(o0[reg] * rcp);
        O[base + 32] = f2bf(o1[reg] * rcp);
    }
}

// ---------------- FC + tanh: rows ordered (b, q, h), packed f32x4 stores ---
__global__ __launch_bounds__(256) void fc_kernel(const unsigned short* __restrict__ O,
                                                 const unsigned short* __restrict__ WfcT,
                                                 const float* __restrict__ bfc,
                                                 float* __restrict__ out) {
    int tid = threadIdx.x, w = tid >> 6, lane = tid & 63;
    int l15 = lane & 15, l4 = lane >> 4;
    int r0 = blockIdx.x * 64 + w * 16;

    int row = r0 + l15;
    int h = row & 15, t_ = row >> 4;
    int q = t_ & 2047, b = t_ >> 11;
    const unsigned short* op = O + (((size_t)(b * NH + h)) * SEQ + q) * 64 + l4 * 8;
    bf16x8 a0 = ld8(op), a1 = ld8(op + 32);

    for (int ct = 0; ct < 4; ++ct) {
        const unsigned short* wp = WfcT + (ct * 16 + l15) * 64 + l4 * 8;
        bf16x8 b0 = ld8(wp), b1 = ld8(wp + 32);
        f32x4 acc = {0.f, 0.f, 0.f, 0.f};
        acc = __builtin_amdgcn_mfma_f32_16x16x32_bf16(b0, a0, acc, 0, 0, 0);
        acc = __builtin_amdgcn_mfma_f32_16x16x32_bf16(b1, a1, acc, 0, 0, 0);
        f32x4 bv = *reinterpret_cast<const f32x4*>(bfc + ct * 16 + l4 * 4);
        f32x4 st;
        #pragma unroll
        for (int r = 0; r < 4; ++r) {
            float x = acc[r] + bv[r];
            x = fminf(fmaxf(x, -9.f), 9.f);
            float t = fexp2(x * 2.88539008177793f);     // 2*log2(e)
            st[r] = (t - 1.f) * __builtin_amdgcn_rcpf(t + 1.f);
        }
        *reinterpret_cast<f32x4*>(out + (size_t)row * 64 + ct * 16 + l4 * 4) = st;
    }
}

extern "C" void kernel_launch(void* const* d_in, const int* in_sizes, int n_in,
                              void* d_out, int out_size, void* d_ws, size_t ws_size,
                              hipStream_t stream) {
    const float* q_origin = (const float*)d_in[0];
    const float* k_origin = (const float*)d_in[1];
    const int*   mask     = (const int*)d_in[2];
    const float* Wq       = (const float*)d_in[3];
    const float* Wk       = (const float*)d_in[4];
    const float* Wv       = (const float*)d_in[5];
    const float* Wfc      = (const float*)d_in[6];
    const float* bfc      = (const float*)d_in[7];
    float* out = (float*)d_out;

    unsigned short* ws = (unsigned short*)d_ws;
    unsigned short* qbf  = ws;                 // dead after proj
    unsigned short* kbf  = qbf  + TOK * DH;    // dead after proj
    unsigned short* WqT  = kbf  + TOK * DH;
    unsigned short* WkT  = WqT  + 64 * PROJC;
    unsigned short* WvT  = WkT  + 64 * PROJC;
    unsigned short* WfcT = WvT  + 64 * PROJC;
    unsigned short* Qb   = WfcT + 64 * 64;
    unsigned short* Kb   = Qb   + (size_t)BSZ * NH * SEQ * DH;
    unsigned short* Vtb  = Kb   + (size_t)BSZ * NH * SEQ * DH;
    unsigned short* Ob   = Vtb  + (size_t)BSZ * NH * SEQ * DH;
    unsigned long long* mbits = (unsigned long long*)d_ws;  // aliases qbf/kbf

    prep_kernel<<<4880, 256, 0, stream>>>(q_origin, k_origin, Wq, Wk, Wv, Wfc,
                                          qbf, kbf, WqT, WkT, WvT, WfcT);
    proj_kernel<<<dim3(TOK / 64, NH), 256, 0, stream>>>(
        qbf, kbf, WqT, WkT, WvT, Qb, Kb, Vtb);
    maskpack_kernel<<<(size_t)BSZ * SEQ * SEQ / 256, 256, 0, stream>>>(mask, mbits);
    attn_kernel<<<512, 512, 0, stream>>>(Qb, Kb, Vtb, mbits, Ob);
    fc_kernel<<<(size_t)BSZ * SEQ * NH / 64, 256, 0, stream>>>(Ob, WfcT, bfc, out);
}

// Round 15
// 166.343 us; speedup vs baseline: 1.1277x; 1.0523x over previous
//
#include <hip/hip_runtime.h>
#include <hip/hip_bf16.h>

// Problem constants
#define BSZ 4
#define SEQ 2048
#define NH  16
#define DH  64
#define TOK (BSZ*SEQ)          // 8192 tokens
#define PROJC (NH*DH)          // 1024

typedef __bf16 bf16x8 __attribute__((ext_vector_type(8)));
typedef float  f32x4  __attribute__((ext_vector_type(4)));
typedef float  f32x16 __attribute__((ext_vector_type(16)));
typedef unsigned int uint4v __attribute__((ext_vector_type(4)));
typedef unsigned int uint2v __attribute__((ext_vector_type(2)));

__device__ inline unsigned short f2bf(float f) {
    __bf16 h = (__bf16)f;
    return __builtin_bit_cast(unsigned short, h);
}

__device__ inline bf16x8 ld8(const unsigned short* p) {
    return __builtin_bit_cast(bf16x8, *reinterpret_cast<const uint4v*>(p));
}

// raw v_exp_f32 (2^x): 1 instruction, no OCML range/denorm guards.
__device__ inline float fexp2(float x) {
    float r;
    asm("v_exp_f32 %0, %1" : "=v"(r) : "v"(x));
    return r;
}

// async global -> LDS, 16B per lane; LDS dest = wave-uniform base + lane*16
__device__ inline void gload16(const unsigned short* g, unsigned short* l) {
    __builtin_amdgcn_global_load_lds(
        (__attribute__((address_space(1))) void*)g,
        (__attribute__((address_space(3))) void*)l, 16, 0, 0);
}

// ---------------- fused prep: conv (f32->bf16) + 4x weight transpose -------
__global__ __launch_bounds__(256) void prep_kernel(const float* __restrict__ q,
                                                   const float* __restrict__ k,
                                                   const float* __restrict__ Wq,
                                                   const float* __restrict__ Wk,
                                                   const float* __restrict__ Wv,
                                                   const float* __restrict__ Wfc,
                                                   unsigned short* __restrict__ qbf,
                                                   unsigned short* __restrict__ kbf,
                                                   unsigned short* __restrict__ WqT,
                                                   unsigned short* __restrict__ WkT,
                                                   unsigned short* __restrict__ WvT,
                                                   unsigned short* __restrict__ WfcT) {
    int bx = blockIdx.x;
    if (bx < 4096) {
        int idx = (bx & 2047) * 256 + threadIdx.x;
        if (bx < 2048) qbf[idx] = f2bf(q[idx]);
        else           kbf[idx] = f2bf(k[idx]);
        return;
    }
    bx -= 4096;
    const float* W; unsigned short* WT; int cols; int base;
    if      (bx < 256) { W = Wq;  WT = WqT;  cols = PROJC; base = bx; }
    else if (bx < 512) { W = Wk;  WT = WkT;  cols = PROJC; base = bx - 256; }
    else if (bx < 768) { W = Wv;  WT = WvT;  cols = PROJC; base = bx - 512; }
    else               { W = Wfc; WT = WfcT; cols = 64;    base = bx - 768; }
    int idx = base * 256 + threadIdx.x;
    int c = idx % cols, kk = idx / cols;
    WT[c * 64 + kk] = f2bf(W[kk * cols + c]);
}

// ---------------- mask bit-pack: int32 [b][q][k] -> uint64 bitrows ---------
__global__ __launch_bounds__(256) void maskpack_kernel(const int* __restrict__ mask,
                                                       unsigned long long* __restrict__ mbits) {
    size_t gid = (size_t)blockIdx.x * 256 + threadIdx.x;
    int lane = threadIdx.x & 63;
    unsigned long long bal = __ballot(mask[gid] != 0);
    if (lane == 0) mbits[gid >> 6] = bal;
}

// ---------------- fused projections: Q, K, Vt in one pass ------------------
__global__ __launch_bounds__(256) void proj_kernel(const unsigned short* __restrict__ qbf,
                                                   const unsigned short* __restrict__ kbf,
                                                   const unsigned short* __restrict__ WqT,
                                                   const unsigned short* __restrict__ WkT,
                                                   const unsigned short* __restrict__ WvT,
                                                   unsigned short* __restrict__ Qo,
                                                   unsigned short* __restrict__ Ko,
                                                   unsigned short* __restrict__ Vto) {
    __shared__ __align__(16) unsigned short TQ[64][72];
    __shared__ __align__(16) unsigned short TK[64][72];
    __shared__ __align__(16) unsigned short TV[64][72];
    int tid = threadIdx.x, w = tid >> 6, lane = tid & 63;
    int l15 = lane & 15, l4 = lane >> 4;
    int r0 = blockIdx.x * 64 + w * 16;
    int h = blockIdx.y;
    int c0 = h * 64;
    int b = blockIdx.x >> 5;
    size_t bh = (size_t)(b * NH + h);

    const unsigned short* aq = qbf + (r0 + l15) * 64 + l4 * 8;
    bf16x8 a0q = ld8(aq), a1q = ld8(aq + 32);
    const unsigned short* ak = kbf + (r0 + l15) * 64 + l4 * 8;
    bf16x8 a0k = ld8(ak), a1k = ld8(ak + 32);

    #pragma unroll
    for (int ct = 0; ct < 4; ++ct) {
        int wrow = (c0 + ct * 16 + l15) * 64 + l4 * 8;
        bf16x8 q0 = ld8(WqT + wrow), q1 = ld8(WqT + wrow + 32);
        bf16x8 k0 = ld8(WkT + wrow), k1 = ld8(WkT + wrow + 32);
        bf16x8 v0 = ld8(WvT + wrow), v1 = ld8(WvT + wrow + 32);
        f32x4 accq = {0.f,0.f,0.f,0.f}, acck = accq, accv = accq;
        accq = __builtin_amdgcn_mfma_f32_16x16x32_bf16(q0, a0q, accq, 0, 0, 0);
        accq = __builtin_amdgcn_mfma_f32_16x16x32_bf16(q1, a1q, accq, 0, 0, 0);
        acck = __builtin_amdgcn_mfma_f32_16x16x32_bf16(k0, a0k, acck, 0, 0, 0);
        acck = __builtin_amdgcn_mfma_f32_16x16x32_bf16(k1, a1k, acck, 0, 0, 0);
        accv = __builtin_amdgcn_mfma_f32_16x16x32_bf16(a0k, v0, accv, 0, 0, 0);
        accv = __builtin_amdgcn_mfma_f32_16x16x32_bf16(a1k, v1, accv, 0, 0, 0);
        uint2v pq, pk, pv;
        pq.x = (unsigned)f2bf(accq[0]) | ((unsigned)f2bf(accq[1]) << 16);
        pq.y = (unsigned)f2bf(accq[2]) | ((unsigned)f2bf(accq[3]) << 16);
        pk.x = (unsigned)f2bf(acck[0]) | ((unsigned)f2bf(acck[1]) << 16);
        pk.y = (unsigned)f2bf(acck[2]) | ((unsigned)f2bf(acck[3]) << 16);
        pv.x = (unsigned)f2bf(accv[0]) | ((unsigned)f2bf(accv[1]) << 16);
        pv.y = (unsigned)f2bf(accv[2]) | ((unsigned)f2bf(accv[3]) << 16);
        *reinterpret_cast<uint2v*>(&TQ[w * 16 + l15][ct * 16 + l4 * 4]) = pq;
        *reinterpret_cast<uint2v*>(&TK[w * 16 + l15][ct * 16 + l4 * 4]) = pk;
        *reinterpret_cast<uint2v*>(&TV[ct * 16 + l15][w * 16 + l4 * 4]) = pv;
    }
    __syncthreads();

    int rl8 = tid >> 3, chunk = tid & 7;
    int q0 = (blockIdx.x & 31) * 64;
    #pragma unroll
    for (int p = 0; p < 2; ++p) {
        int rl = p * 32 + rl8;
        uint4v vq = *reinterpret_cast<const uint4v*>(&TQ[rl][chunk * 8]);
        uint4v vk = *reinterpret_cast<const uint4v*>(&TK[rl][chunk * 8]);
        uint4v vv = *reinterpret_cast<const uint4v*>(&TV[rl][chunk * 8]);
        *reinterpret_cast<uint4v*>(Qo  + (bh * SEQ + q0 + rl) * 64 + chunk * 8) = vq;
        *reinterpret_cast<uint4v*>(Ko  + (bh * SEQ + q0 + rl) * 64 + chunk * 8) = vk;
        *reinterpret_cast<uint4v*>(Vto + (bh * 64 + rl) * SEQ + q0 + chunk * 8) = vv;
    }
}

// ---------------- flash attention + fused FC/tanh epilogue -----------------
// Grid 512 (XCD-swizzled), 512 threads = 8 waves, 32 q rows per wave; 8
// waves share one K/V staging. K/V [64][64] double-buffered via
// global_load_lds; kb-loop unrolled x2. Swapped QK^T; PV A-frag = lane's own
// packed words; ell via ones-MFMA. Static max m=0; fully-masked -> ell==0.
// EPILOGUE (new): normalized bf16 O goes to a wave-private XOR-swizzled LDS
// tile (wave-local write->read, in-order DS pipe -- same discipline as the
// verified R3-R7 P-LDS path), re-read as B-frags (lane=q), then
// out = tanh(O @ Wfc + bfc) via 8 mfma + packed dwordx4 stores.
__global__ __launch_bounds__(512, 4) void attn_kernel(const unsigned short* __restrict__ Q,
                                                      const unsigned short* __restrict__ K,
                                                      const unsigned short* __restrict__ Vt,
                                                      const unsigned long long* __restrict__ mbits,
                                                      const unsigned short* __restrict__ WfcT,
                                                      const float* __restrict__ bfc,
                                                      float* __restrict__ out) {
    __shared__ __align__(16) unsigned short Ks[2][64 * 64];   // 16 KB
    __shared__ __align__(16) unsigned short Vs[2][64 * 64];   // 16 KB
    int tid = threadIdx.x, w = tid >> 6, lane = tid & 63;
    int l31 = lane & 31, hi = lane >> 5;
    int hi4 = hi * 4;

    // XCD-aware swizzle: 512 % 8 == 0, bijective
    int bid = blockIdx.x;
    int swz = (bid & 7) * 64 + (bid >> 3);
    int bh = swz >> 3;              // 0..63
    int qt = swz & 7;               // 0..7
    int b = bh >> 4;
    int qbase = qt * 256 + w * 32;

    const unsigned short* Qh = Q  + (size_t)bh * SEQ * 64;
    const unsigned short* Kh = K  + (size_t)bh * SEQ * 64;
    const unsigned short* Vh = Vt + (size_t)bh * 64 * SEQ;
    const unsigned long long* mrow =
        mbits + ((size_t)b * SEQ + qbase + l31) * (SEQ / 64);

    // staging: 512 threads x 16B = full 8KB tile in one pass
    int row1 = (w << 3) + (lane >> 3);          // 0..63 across 8 waves
    int sc1 = (lane & 7) ^ (row1 & 7);          // source chunk (XOR involution)
    unsigned short* Kd0 = &Ks[0][0] + w * 512;
    unsigned short* Vd0 = &Vs[0][0] + w * 512;
    unsigned short* Kd1 = &Ks[1][0] + w * 512;
    unsigned short* Vd1 = &Vs[1][0] + w * 512;

    // Q B-frags: lane holds Q[qbase+l31][s*16 + hi*8 + j]
    bf16x8 qf[4];
    #pragma unroll
    for (int s = 0; s < 4; ++s)
        qf[s] = ld8(Qh + (size_t)(qbase + l31) * 64 + s * 16 + hi * 8);

    bf16x8 ones;
    #pragma unroll
    for (int i = 0; i < 8; ++i) ones[i] = (__bf16)1.0f;

    f32x16 o0 = {0.f,0.f,0.f,0.f,0.f,0.f,0.f,0.f,0.f,0.f,0.f,0.f,0.f,0.f,0.f,0.f};
    f32x16 o1 = o0;
    f32x16 ellD = o0;
    const float C = 0.125f * 1.44269504088896f;   // scale * log2(e)

    auto stage_tile = [&](unsigned short* Kd, unsigned short* Vd, int nkb) {
        gload16(Kh + (size_t)(nkb + row1) * 64 + sc1 * 8, Kd);
        gload16(Vh + (size_t)row1 * SEQ + nkb + sc1 * 8, Vd);
    };

    auto compute_tile = [&](const unsigned short* Kc, const unsigned short* Vc, int kb) {
        unsigned long long wb = mrow[kb >> 6];
        #pragma unroll
        for (int kt = 0; kt < 2; ++kt) {
            f32x16 z = {0.f,0.f,0.f,0.f,0.f,0.f,0.f,0.f,0.f,0.f,0.f,0.f,0.f,0.f,0.f,0.f};
            int krow = kt * 32 + l31;
            #pragma unroll
            for (int s = 0; s < 4; ++s) {
                const unsigned short* kp =
                    Kc + krow * 64 + ((((s << 1) + hi) ^ (krow & 7)) << 3);
                z = __builtin_amdgcn_mfma_f32_32x32x16_bf16(ld8(kp), qf[s], z, 0, 0, 0);
            }
            unsigned wsh = (unsigned)(wb >> (kt * 32)) >> hi4;  // lane's bits 0..27
            unsigned wpk[8];
            #pragma unroll
            for (int rq = 0; rq < 4; ++rq) {
                #pragma unroll
                for (int rr = 0; rr < 2; ++rr) {
                    float e[2];
                    #pragma unroll
                    for (int j = 0; j < 2; ++j) {
                        int pos = rq * 8 + 2 * rr + j;           // compile-time
                        int sx = (int)(wsh << (31 - pos)) >> 31; // v_bfe_i32
                        float bias = __builtin_bit_cast(float, (unsigned)sx & 0xFF800000u);
                        e[j] = fexp2(__builtin_fmaf(z[rq * 4 + 2 * rr + j], C, bias));
                    }
                    wpk[rq * 2 + rr] = (unsigned)f2bf(e[0]) | ((unsigned)f2bf(e[1]) << 16);
                }
            }
            __builtin_amdgcn_s_setprio(1);
            #pragma unroll
            for (int sl = 0; sl < 2; ++sl) {
                uint4v aw = {wpk[sl * 4 + 0], wpk[sl * 4 + 1],
                             wpk[sl * 4 + 2], wpk[sl * 4 + 3]};
                bf16x8 af = __builtin_bit_cast(bf16x8, aw);
                ellD = __builtin_amdgcn_mfma_f32_32x32x16_bf16(af, ones, ellD, 0, 0, 0);
                int n = kt * 2 + sl;            // k-subtile of 16 within kb
                {   // dtile 0
                    int vrow = l31;
                    int c0i = ((2 * n) ^ (vrow & 7)) << 3;
                    int c1i = ((2 * n + 1) ^ (vrow & 7)) << 3;
                    uint2v lo = *reinterpret_cast<const uint2v*>(Vc + vrow * 64 + c0i + hi4);
                    uint2v hh = *reinterpret_cast<const uint2v*>(Vc + vrow * 64 + c1i + hi4);
                    uint4v vw = {lo.x, lo.y, hh.x, hh.y};
                    o0 = __builtin_amdgcn_mfma_f32_32x32x16_bf16(
                        af, __builtin_bit_cast(bf16x8, vw), o0, 0, 0, 0);
                }
                {   // dtile 1
                    int vrow = 32 + l31;
                    int c0i = ((2 * n) ^ (vrow & 7)) << 3;
                    int c1i = ((2 * n + 1) ^ (vrow & 7)) << 3;
                    uint2v lo = *reinterpret_cast<const uint2v*>(Vc + vrow * 64 + c0i + hi4);
                    uint2v hh = *reinterpret_cast<const uint2v*>(Vc + vrow * 64 + c1i + hi4);
                    uint4v vw = {lo.x, lo.y, hh.x, hh.y};
                    o1 = __builtin_amdgcn_mfma_f32_32x32x16_bf16(
                        af, __builtin_bit_cast(bf16x8, vw), o1, 0, 0, 0);
                }
            }
            __builtin_amdgcn_s_setprio(0);
        }
    };

    // prologue: stage kb=0 into buffer 0
    stage_tile(Kd0, Vd0, 0);
    __syncthreads();

    for (int kb = 0; kb < SEQ; kb += 128) {
        stage_tile(Kd1, Vd1, kb + 64);
        compute_tile(&Ks[0][0], &Vs[0][0], kb);
        __syncthreads();
        if (kb + 128 < SEQ) stage_tile(Kd0, Vd0, kb + 128);
        compute_tile(&Ks[1][0], &Vs[1][0], kb + 64);
        __syncthreads();
    }

    // ==== fused epilogue: out = tanh(O @ Wfc + bfc) ====
    // wave-private 4KB LDS tile (reuse Ks/Vs; loop's final barrier passed)
    unsigned short* Ot = ((w < 4) ? &Ks[0][0] : &Vs[0][0]) + (w & 3) * 2048;

    // write normalized bf16 O, XOR-chunk swizzle: chunk ^= (q & 7)
    #pragma unroll
    for (int reg = 0; reg < 16; ++reg) {
        float l = ellD[reg];
        float rcp = (l == 0.f) ? 0.f : __builtin_amdgcn_rcpf(l);
        int ql = (reg & 3) + 8 * (reg >> 2) + hi4;   // 0..31
        int ch0 = (l31 >> 3) ^ (ql & 7);
        int ch1 = ((l31 >> 3) + 4) ^ (ql & 7);
        Ot[ql * 64 + ch0 * 8 + (l31 & 7)] = f2bf(o0[reg] * rcp);
        Ot[ql * 64 + ch1 * 8 + (l31 & 7)] = f2bf(o1[reg] * rcp);
    }
    // read B-frags: lane=q=l31 holds O[q][dd = s*16 + hi*8 + j]
    bf16x8 of[4];
    #pragma unroll
    for (int s = 0; s < 4; ++s) {
        int cs = (s * 2 + hi) ^ (l31 & 7);
        of[s] = ld8(Ot + l31 * 64 + cs * 8);
    }
    // FC: A = WfcT[c][dd] (same A-frag mapping as K in QK^T), B = O
    int qrow = qbase + l31;
    size_t orow = ((size_t)b * SEQ + qrow) * NH + (bh & 15);
    #pragma unroll
    for (int ctile = 0; ctile < 2; ++ctile) {
        f32x16 acc = {0.f,0.f,0.f,0.f,0.f,0.f,0.f,0.f,0.f,0.f,0.f,0.f,0.f,0.f,0.f,0.f};
        #pragma unroll
        for (int s = 0; s < 4; ++s) {
            bf16x8 wf = ld8(WfcT + (ctile * 32 + l31) * 64 + s * 16 + hi * 8);
            acc = __builtin_amdgcn_mfma_f32_32x32x16_bf16(wf, of[s], acc, 0, 0, 0);
        }
        #pragma unroll
        for (int g = 0; g < 4; ++g) {   // regs 4g..4g+3 -> c = ctile*32+8g+4hi+0..3
            int cbase = ctile * 32 + 8 * g + hi4;
            f32x4 bv = *reinterpret_cast<const f32x4*>(bfc + cbase);
            f32x4 st;
            #pragma unroll
            for (int r = 0; r < 4; ++r) {
                float x = acc[g * 4 + r] + bv[r];
                x = fminf(fmaxf(x, -9.f), 9.f);
                float t = fexp2(x * 2.88539008177793f);     // 2*log2(e)
                st[r] = (t - 1.f) * __builtin_amdgcn_rcpf(t + 1.f);
            }
            *reinterpret_cast<f32x4*>(out + orow * 64 + cbase) = st;
        }
    }
}

extern "C" void kernel_launch(void* const* d_in, const int* in_sizes, int n_in,
                              void* d_out, int out_size, void* d_ws, size_t ws_size,
                              hipStream_t stream) {
    const float* q_origin = (const float*)d_in[0];
    const float* k_origin = (const float*)d_in[1];
    const int*   mask     = (const int*)d_in[2];
    const float* Wq       = (const float*)d_in[3];
    const float* Wk       = (const float*)d_in[4];
    const float* Wv       = (const float*)d_in[5];
    const float* Wfc      = (const float*)d_in[6];
    const float* bfc      = (const float*)d_in[7];
    float* out = (float*)d_out;

    unsigned short* ws = (unsigned short*)d_ws;
    unsigned short* qbf  = ws;                 // dead after proj
    unsigned short* kbf  = qbf  + TOK * DH;    // dead after proj
    unsigned short* WqT  = kbf  + TOK * DH;
    unsigned short* WkT  = WqT  + 64 * PROJC;
    unsigned short* WvT  = WkT  + 64 * PROJC;
    unsigned short* WfcT = WvT  + 64 * PROJC;
    unsigned short* Qb   = WfcT + 64 * 64;
    unsigned short* Kb   = Qb   + (size_t)BSZ * NH * SEQ * DH;
    unsigned short* Vtb  = Kb   + (size_t)BSZ * NH * SEQ * DH;
    unsigned long long* mbits = (unsigned long long*)d_ws;  // aliases qbf/kbf

    prep_kernel<<<4880, 256, 0, stream>>>(q_origin, k_origin, Wq, Wk, Wv, Wfc,
                                          qbf, kbf, WqT, WkT, WvT, WfcT);
    proj_kernel<<<dim3(TOK / 64, NH), 256, 0, stream>>>(
        qbf, kbf, WqT, WkT, WvT, Qb, Kb, Vtb);
    maskpack_kernel<<<(size_t)BSZ * SEQ * SEQ / 256, 256, 0, stream>>>(mask, mbits);
    attn_kernel<<<512, 512, 0, stream>>>(Qb, Kb, Vtb, mbits, WfcT, bfc, out);
}